// Round 12
// baseline (353.646 us; speedup 1.0000x reference)
//
#include <hip/hip_runtime.h>

// LSTM, MFMA formulation. Round 18: hidden-split 2-wave blocks.
// B=4096, T=512, I=10, H=32, O=1. Gates i,f,g,o.
//
// R17 post-mortem: 2 waves/SIMD at dup-8 = 259us (MfmaUtil 46, sum 94%):
// overlap partially engaged but doubled MFMA/batch ate it. Rule confirmed
// 3x: never add MFMAs per batch.
//
// R18: split H across 2 waves of one block. Wave wid in {0,1}:
//   - computes gate-tiles {2*gt + wid} (gates' rows 32gt+16wid..+16wid+15)
//     = 8 MFMAs/step: total MFMAs per 4 batches UNCHANGED (16).
//   - act: 1 cell/lane (batch Q, hid L+16wid), 5 exp2 + 3 rcp (R13 algebra).
//   - grid 1024 blocks x 128 thr = 2048 waves = 2 waves/SIMD, full chip.
//     Block's 2 waves land on different SIMDs; each SIMD hosts waves of 2
//     DIFFERENT blocks (unsynchronized) -> phase diversity -> mutual
//     stall-filling, no duplication, no stagger hacks.
//   - coupling: full h needed by both waves' A-frags -> shared LDS h,
//     double-buffered, ONE __syncthreads per step (write->barrier->read;
//     write of step k targets the buffer read at k-1, safe both ways).
//
// Per-SIMD per step: VALU-issue ~480 (2 waves) + MFMA-issue 64; MFMA pipe
// 304; chain ~450 -> overlapped window ~550-700 vs R13's 1070.
//
// Mappings (R9/R13-verified): A row m = L (batch L>>2, dup-4), A[m][k=8Q+j];
// C col=L, row=4Q+reg, keep reg 0 -> batch Q, W-row 32gt+16wid+L ->
// cell (batch Q, hid L+16wid). Merged-K (R9): MFMA1 A={x_hat k0..9 |
// h_lo k10..31}, MFMA2 A=h_hi. Shared-denominator act (R13). fp16 2-term
// h split, lo dropped ch0..9 (absmax 2e-3 verified R9-R17). Biases folded.

#define T_SZ 512
#define I_SZ 10
#define H_SZ 32

typedef _Float16 half8  __attribute__((ext_vector_type(8)));
typedef __fp16   fp16x2 __attribute__((ext_vector_type(2)));
typedef float    f32x4  __attribute__((ext_vector_type(4)));
typedef int      i32x4  __attribute__((ext_vector_type(4)));

union FH { i32x4 i; half8 h; };
static __device__ __forceinline__ half8 fragv(i32x4 v) { FH u; u.i = v; return u.h; }
static __device__ __forceinline__ half8 frag4(int a, int b, int c, int d) {
    FH u; u.i = (i32x4){a, b, c, d}; return u.h;
}

// pack 2 fp32 -> 2 fp16 in one dword (v_cvt_pkrtz_f16_f32)
static __device__ __forceinline__ int pk16(float lo, float hi) {
    union { fp16x2 h; int i; } u;
    u.h = __builtin_amdgcn_cvt_pkrtz(lo, hi);
    return u.i;
}

#define MFMAH(A, B, C) __builtin_amdgcn_mfma_f32_16x16x32_f16((A), (B), (C), 0, 0, 0)
#define EXP2(x) __builtin_amdgcn_exp2f(x)
#define RCP(x)  __builtin_amdgcn_rcpf(x)

__global__ __launch_bounds__(128, 2)
void lstm_wave(const float* __restrict__ x, const float* __restrict__ W_ih,
               const float* __restrict__ W_hh, const float* __restrict__ b_ih,
               const float* __restrict__ b_hh, const float* __restrict__ W_dense,
               const float* __restrict__ b_dense, float* __restrict__ out)
{
    const int tid   = threadIdx.x;        // 0..127 (2 waves)
    const int lane  = tid & 63;
    const int wid   = tid >> 6;           // 0: hid 0-15, 1: hid 16-31
    const int L     = lane & 15;          // A m-row / C col
    const int Q     = lane >> 4;          // k-quad / C row-quad (= act batch)
    const int bbase = blockIdx.x * 4;     // 1024 blocks x 4 batches

    const int bA  = L >> 2;               // A-side batch (4 dup rows per batch)
    const int hid = L + 16 * wid;         // this lane's hidden channel

    // ---- B-fragments for this wave's 4 gate-tiles (one-time) ----
    // gate gt tile: W row = 32*gt + 16*wid + L
    int bhh[4][4];
    int bm[4][4];
    #pragma unroll
    for (int gt = 0; gt < 4; ++gt) {
        const int wr = 32 * gt + 16 * wid + L;
        const float* ph = W_hh + wr * H_SZ + 8 * Q;
        #pragma unroll
        for (int d = 0; d < 4; ++d) {
            float2 v = *(const float2*)(ph + 2 * d);
            bhh[gt][d] = pk16(v.x, v.y);
        }
        if (Q == 0) {
            const float* pi = W_ih + wr * I_SZ;       // k0..7 = W_ih cols 0..7
            #pragma unroll
            for (int d = 0; d < 4; ++d) {
                float2 v = *(const float2*)(pi + 2 * d);
                bm[gt][d] = pk16(v.x, v.y);
            }
        } else if (Q == 1) {
            // k8,9 = W_ih cols 8,9; k10..15 = W_hh cols 10..15
            float2 v = *(const float2*)(W_ih + wr * I_SZ + 8);
            bm[gt][0] = pk16(v.x, v.y);
            #pragma unroll
            for (int d = 1; d < 4; ++d) {
                float2 w = *(const float2*)(W_hh + wr * H_SZ + 8 + 2 * d);
                bm[gt][d] = pk16(w.x, w.y);
            }
        } else {
            bm[gt][0] = bhh[gt][0]; bm[gt][1] = bhh[gt][1];
            bm[gt][2] = bhh[gt][2]; bm[gt][3] = bhh[gt][3];
        }
    }

    // ---- biases folded into exp2 args (this lane's cell) ----
    const float nL = -1.4426950f;     // -log2(e)       (sigmoid)
    const float m2 = -2.8853901f;     // -2*log2(e)     (tanh via (1-D)/(1+D))
    const float mbi = nL * (b_ih[hid]      + b_hh[hid]);
    const float mbf = nL * (b_ih[32 + hid] + b_hh[32 + hid]);
    const float mbg = m2 * (b_ih[64 + hid] + b_hh[64 + hid]);
    const float mbo = nL * (b_ih[96 + hid] + b_hh[96 + hid]);

    // ---- block-shared LDS h buffer: [buf][plane hi/lo][batch 0..3][hid] ----
    __shared__ __attribute__((aligned(16))) _Float16 hbuf[2][2][4][H_SZ];  // 1 KiB
    __shared__ float redbuf[2][4];
    {
        int* zz = (int*)&hbuf[0][0][0][0];
        zz[tid] = 0; zz[tid + 128] = 0;   // 256 ints total
    }
    __syncthreads();                      // zeros visible to both waves

    // ---- x stream: 2-deep prefetch (each lane loads its A-side batch row) ----
    const float* xrow = x + (size_t)(bbase + bA) * (T_SZ * I_SZ);
    float2 xa0 = *(const float2*)(xrow + 0), xa1 = *(const float2*)(xrow + 2),
           xa2 = *(const float2*)(xrow + 4), xa3 = *(const float2*)(xrow + 6),
           xa4 = *(const float2*)(xrow + 8);
    float2 xb0 = *(const float2*)(xrow + I_SZ + 0), xb1 = *(const float2*)(xrow + I_SZ + 2),
           xb2 = *(const float2*)(xrow + I_SZ + 4), xb3 = *(const float2*)(xrow + I_SZ + 6),
           xb4 = *(const float2*)(xrow + I_SZ + 8);

    const f32x4 zerov = {0.f, 0.f, 0.f, 0.f};
    float cst = 0.0f;
    float hlast = 0.0f;
    const bool q0 = (Q == 0), q1 = (Q == 1);

    for (int t = 0; t < T_SZ; t += 2) {
        #pragma unroll
        for (int u = 0; u < 2; ++u) {
            const int rb = u, wb = u ^ 1;

            // h fragments from shared LDS (A-frag order, broadcast reads)
            i32x4 hhi_ = *(const i32x4*)&hbuf[rb][0][bA][8 * Q];
            i32x4 lo_  = *(const i32x4*)&hbuf[rb][1][bA][8 * Q];

            // x_hat packs (u is compile-time; selects fold away)
            float2 y0 = u ? xb0 : xa0, y1 = u ? xb1 : xa1, y2 = u ? xb2 : xa2,
                   y3 = u ? xb3 : xa3, y4 = u ? xb4 : xa4;
            int p0 = pk16(y0.x, y0.y), p1 = pk16(y1.x, y1.y), p2 = pk16(y2.x, y2.y),
                p3 = pk16(y3.x, y3.y), p4 = pk16(y4.x, y4.y);

            // merged A-frag: k0..9 = x_hat, k10..31 = h_lo channels 10..31
            half8 mf = fragv((i32x4){ q0 ? p0 : (q1 ? p4 : lo_[0]),
                                      q0 ? p1 : lo_[1],
                                      q0 ? p2 : lo_[2],
                                      q0 ? p3 : lo_[3] });
            half8 hhi = fragv(hhi_);

            // refill consumed x set from t+2+u
            if (t + 2 + u < T_SZ) {
                const float* xr = xrow + (t + 2 + u) * I_SZ;
                if (u == 0) {
                    xa0 = *(const float2*)(xr + 0); xa1 = *(const float2*)(xr + 2);
                    xa2 = *(const float2*)(xr + 4); xa3 = *(const float2*)(xr + 6);
                    xa4 = *(const float2*)(xr + 8);
                } else {
                    xb0 = *(const float2*)(xr + 0); xb1 = *(const float2*)(xr + 2);
                    xb2 = *(const float2*)(xr + 4); xb3 = *(const float2*)(xr + 6);
                    xb4 = *(const float2*)(xr + 8);
                }
            }

            // ---- this wave's 4 gate tile-pairs, exp2 pipelined 1 pair back --
            f32x4 a0 = MFMAH(mf,  frag4(bm[0][0],  bm[0][1],  bm[0][2],  bm[0][3]),  zerov);
            a0       = MFMAH(hhi, frag4(bhh[0][0], bhh[0][1], bhh[0][2], bhh[0][3]), a0);
            f32x4 a1 = MFMAH(mf,  frag4(bm[1][0],  bm[1][1],  bm[1][2],  bm[1][3]),  zerov);
            a1       = MFMAH(hhi, frag4(bhh[1][0], bhh[1][1], bhh[1][2], bhh[1][3]), a1);
            float eA = EXP2(fmaf(nL, a0[0], mbi));        // i-gate
            f32x4 a2 = MFMAH(mf,  frag4(bm[2][0],  bm[2][1],  bm[2][2],  bm[2][3]),  zerov);
            a2       = MFMAH(hhi, frag4(bhh[2][0], bhh[2][1], bhh[2][2], bhh[2][3]), a2);
            float eF = EXP2(fmaf(nL, a1[0], mbf));        // f-gate
            f32x4 a3 = MFMAH(mf,  frag4(bm[3][0],  bm[3][1],  bm[3][2],  bm[3][3]),  zerov);
            a3       = MFMAH(hhi, frag4(bhh[3][0], bhh[3][1], bhh[3][2], bhh[3][3]), a3);
            float eG = EXP2(fmaf(m2, a2[0], mbg));        // g-gate
            float eO = EXP2(fmaf(nL, a3[0], mbo));        // o-gate

            // ---- combine (shared-denominator gates, 3 rcp) ----
            // i*g~ = (1-B)/((1+A)(1+B)); f = 1/(1+F); h = (1-D)/((1+O)(1+D))
            float fg  = RCP(1.0f + eF);
            float igg = (1.0f - eG) * RCP((1.0f + eA) * (1.0f + eG));
            cst = fmaf(fg, cst, igg);
            float eD = EXP2(m2 * cst);
            float hv = (1.0f - eD) * RCP((1.0f + eO) * (1.0f + eD));
            hlast = hv;

            // h write-back, fp16 2-term split
            _Float16 hh = (_Float16)hv;
            _Float16 hl = (_Float16)(hv - (float)hh);
            hbuf[wb][0][Q][hid] = hh;
            hbuf[wb][1][Q][hid] = hl;

            // one barrier per step: writes of both waves visible before the
            // next iteration's reads (writes of iter k+1 target the buffer
            // read at iter k-1 -> safe on both sides of the barrier)
            __syncthreads();
        }
    }

    // ---- dense head: out[b] = h . W_dense + b_dense ----
    // lane (Q,L) of wave wid holds h(batch Q, hid L+16wid)
    float v = hlast * W_dense[hid];
    #pragma unroll
    for (int m = 8; m >= 1; m >>= 1)
        v += __shfl_xor(v, m);            // reduce within each 16-lane quad
    if (L == 0) redbuf[wid][Q] = v;
    __syncthreads();
    if (tid < 4) out[bbase + tid] = redbuf[0][tid] + redbuf[1][tid] + b_dense[0];
}

extern "C" void kernel_launch(void* const* d_in, const int* in_sizes, int n_in,
                              void* d_out, int out_size, void* d_ws, size_t ws_size,
                              hipStream_t stream) {
    const float* x       = (const float*)d_in[0];
    const float* W_ih    = (const float*)d_in[1];
    const float* W_hh    = (const float*)d_in[2];
    const float* b_ih    = (const float*)d_in[3];
    const float* b_hh    = (const float*)d_in[4];
    const float* W_dense = (const float*)d_in[5];
    const float* b_dense = (const float*)d_in[6];
    float* out = (float*)d_out;

    // 1024 blocks x 128 threads = 2048 waves = 2 waves/SIMD; block = 2 waves
    // splitting H (16 hid each) over the same 4 batches
    lstm_wave<<<dim3(1024), dim3(128), 0, stream>>>(
        x, W_ih, W_hh, b_ih, b_hh, W_dense, b_dense, out);
}